// Round 8
// baseline (397.613 us; speedup 1.0000x reference)
//
#include <hip/hip_runtime.h>
#include <cstdint>
#include <cmath>

#define HID 768
#define INNER 1536
#define NST 16
#define SEQ 2048
#define BATCH 2
#define MTOK 4096      // BATCH*SEQ
#define CHUNK 64
#define NCHUNK 32      // SEQ/CHUNK
#define LOG2E 1.44269504088896f

typedef unsigned short u16;
typedef __bf16 bf16x8 __attribute__((ext_vector_type(8)));
typedef float f32x4 __attribute__((ext_vector_type(4)));

__device__ __forceinline__ u16 f2b(float f) {
  union { float f; unsigned u; } a; a.f = f;
  unsigned r = a.u + 0x7FFFu + ((a.u >> 16) & 1u);
  return (u16)(r >> 16);
}

__device__ __forceinline__ float b2f(u16 h) {
  union { unsigned u; float f; } a; a.u = ((unsigned)h) << 16;
  return a.f;
}

__device__ __forceinline__ void gl2lds16(const u16* g, u16* l) {
  __builtin_amdgcn_global_load_lds(
      (const __attribute__((address_space(1))) void*)g,
      (__attribute__((address_space(3))) void*)l, 16, 0, 0);
}

template <int N>
__device__ __forceinline__ void vmwait() {
  if constexpr (N == 0)      asm volatile("s_waitcnt vmcnt(0)" ::: "memory");
  else if constexpr (N == 2) asm volatile("s_waitcnt vmcnt(2)" ::: "memory");
  else if constexpr (N == 3) asm volatile("s_waitcnt vmcnt(3)" ::: "memory");
  else if constexpr (N == 4) asm volatile("s_waitcnt vmcnt(4)" ::: "memory");
  else if constexpr (N == 6) asm volatile("s_waitcnt vmcnt(6)" ::: "memory");
  else static_assert(N == 0, "unsupported vmcnt");
}

// ---------------- merged prologue: LayerNorm + 4x transpose_cvt ----------------
// grid layout (1D):
//   [0, 4096)           LayerNorm rows
//   [4096, 6400)        W_in  768x3072 -> 3072x768   (96 x 24 blocks)
//   [6400, 8896)        W_xp  1536x1568 -> 1664x1536 (52 x 48 blocks, zero-pad)
//   [8896, 11200)       W_so  1536x1536 -> 1536x1536 (48 x 48 blocks)
//   [11200, 12352)      W_out 1536x768  -> 768x1536  (24 x 48 blocks)
__global__ __launch_bounds__(256)
void prologue(const float* __restrict__ x, const float* __restrict__ nw,
              const float* __restrict__ nb, u16* __restrict__ xn,
              const float* __restrict__ W0, u16* __restrict__ T0,
              const float* __restrict__ W1, u16* __restrict__ T1,
              const float* __restrict__ W2, u16* __restrict__ T2,
              const float* __restrict__ W3, u16* __restrict__ T3) {
  __shared__ float tb[32][33];
  __shared__ float r1[4], r2[4];
  const int tid = threadIdx.x;
  int bid = blockIdx.x;

  if (bid < MTOK) {
    // ---- LayerNorm + cast to bf16 ----
    const float* xr = x + (long)bid * HID;
    float v0 = xr[tid], v1 = xr[tid + 256], v2 = xr[tid + 512];
    float s1 = v0 + v1 + v2;
    float s2 = v0 * v0 + v1 * v1 + v2 * v2;
#pragma unroll
    for (int o = 32; o > 0; o >>= 1) { s1 += __shfl_down(s1, o); s2 += __shfl_down(s2, o); }
    if ((tid & 63) == 0) { r1[tid >> 6] = s1; r2[tid >> 6] = s2; }
    __syncthreads();
    s1 = r1[0] + r1[1] + r1[2] + r1[3];
    s2 = r2[0] + r2[1] + r2[2] + r2[3];
    const float mu = s1 * (1.f / HID);
    float var = s2 * (1.f / HID) - mu * mu;
    const float rs = rsqrtf(var + 1e-5f);
    xn[(long)bid * HID + tid]       = f2b((v0 - mu) * rs * nw[tid]       + nb[tid]);
    xn[(long)bid * HID + tid + 256] = f2b((v1 - mu) * rs * nw[tid + 256] + nb[tid + 256]);
    xn[(long)bid * HID + tid + 512] = f2b((v2 - mu) * rs * nw[tid + 512] + nb[tid + 512]);
    return;
  }

  // ---- transpose + cvt: fp32 W[K][N] -> bf16 Wt[Npad][K], zero pad ----
  bid -= MTOK;
  const float* W; u16* Wt; int K, N, nbx;
  if (bid < 2304)       {              W = W0; Wt = T0; K = 768;  N = 3072; nbx = 96; }
  else if (bid < 4800)  { bid -= 2304; W = W1; Wt = T1; K = 1536; N = 1568; nbx = 52; }
  else if (bid < 7104)  { bid -= 4800; W = W2; Wt = T2; K = 1536; N = 1536; nbx = 48; }
  else                  { bid -= 7104; W = W3; Wt = T3; K = 1536; N = 768;  nbx = 24; }
  const int tx = tid & 31, ty = tid >> 5;
  const int n0 = (bid % nbx) * 32, k0 = (bid / nbx) * 32;
#pragma unroll
  for (int r = 0; r < 4; ++r) {
    int kk = k0 + ty + r * 8;
    int nn = n0 + tx;
    tb[ty + r * 8][tx] = (nn < N) ? W[(long)kk * N + nn] : 0.f;
  }
  __syncthreads();
#pragma unroll
  for (int r = 0; r < 4; ++r) {
    int nn = n0 + ty + r * 8;
    int kk = k0 + tx;
    Wt[(long)nn * K + kk] = f2b(tb[tx][ty + r * 8]);
  }
}

// ---------------- GEMM: A[M][K] bf16 row-major, Bt[N][K] bf16, BMxBN tile ------
// 256 threads = 4 waves in 2x2; wave tile (BM/2)x(BN/2); BK=32.
// Ring-3 LDS, depth-2 prefetch with counted vmcnt (tile t+2 staged while
// computing t; tile t+1's loads span two iterations), raw s_barrier,
// 2-bit XOR-swizzled LDS chunks (both-sides: pre-swizzled global source,
// linear DMA dest, swizzled ds_read), bijective chunked XCD remap (m204).
// Buffer-reuse safety: stage at iter t writes buf[(t+2)%3] == buf[(t-1)%3],
// whose reads (iter t-1) are ordered before by the closing barrier.
// EPI 0: cc<1536 -> C0[row*1536+cc]=v (u, f32); else Cb[row*1536+cc-1536]=bf16(v) (gate)
// EPI 1: cc<16 -> Bm, cc<32 -> Cm, cc<Nstore -> delta=softplus
// EPI 2: Cb = bf16(v * silu(gate)), gate = b2f(Eb[row*1536+cc])
// EPI 3: C0[row*768+cc] = v + E0[row*768+cc]
template <int BM, int BN, int EPI>
__global__ __launch_bounds__(256)
void gemm_bt(const u16* __restrict__ A, const u16* __restrict__ Bt,
             float* __restrict__ C0, float* __restrict__ C1, float* __restrict__ C2,
             u16* __restrict__ Cb, const float* __restrict__ E0,
             const u16* __restrict__ Eb, int K, int Nstore) {
  constexpr int WTM = BM / 2;       // wave tile M
  constexpr int WTN = BN / 2;       // wave tile N
  constexpr int FI = WTM / 16;      // A frags per wave
  constexpr int FJ = WTN / 16;      // B frags per wave
  constexpr int NLD = BM / 64 + BN / 64;  // global_load_lds per thread per K-step
  __shared__ u16 As[3][BM * 32];
  __shared__ u16 Bs[3][BN * 32];
  const int tid = threadIdx.x;
  const int lane = tid & 63;
  const int wave = tid >> 6;
  const int wm = wave >> 1, wn = wave & 1;
  const int l16 = lane & 15, l4 = lane >> 4;
  const int swz = (l16 >> 1) & 3;   // row bits [2:1] — XOR swizzle for 16B chunks

  // bijective chunked XCD remap (m204): round-robin dispatch -> contiguous
  // logical ids per XCD, so blocks sharing an A row-panel co-reside in one L2.
  const int nwg = (int)(gridDim.x * gridDim.y);
  const int orig = (int)(blockIdx.y * gridDim.x + blockIdx.x);
  const int q = nwg >> 3, r = nwg & 7, xc = orig & 7;
  const int logical = (xc < r ? xc * (q + 1) : r * (q + 1) + (xc - r) * q) + (orig >> 3);
  const long bm = (long)(logical / (int)gridDim.x) * BM;
  const long bn = (long)(logical % (int)gridDim.x) * BN;

  f32x4 acc[FI][FJ] = {};

  const int r0 = tid >> 2;          // row within 64-row group
  // stored chunk = tid&3 (linear LDS dest); fetch global chunk (tid&3)^sw(row)
  const int kg = ((tid & 3) ^ ((r0 >> 1) & 3)) * 8;

  auto stage = [&](int buf, int k0) {
#pragma unroll
    for (int qq = 0; qq < BM / 64; ++qq)
      gl2lds16(A + (bm + r0 + qq * 64) * K + kg + k0, &As[buf][(qq * 256 + tid) * 8]);
#pragma unroll
    for (int qq = 0; qq < BN / 64; ++qq)
      gl2lds16(Bt + (bn + r0 + qq * 64) * K + kg + k0, &Bs[buf][(qq * 256 + tid) * 8]);
  };

  const int NK = K >> 5;
  stage(0, 0);
  stage(1, 32);
  for (int t = 0; t < NK; ++t) {
    const int b = t % 3;
    if (t + 2 < NK) {
      stage((t + 2) % 3, (t + 2) << 5);  // depth-2: t+1 and t+2 stay in flight
      vmwait<2 * NLD>();                 // oldest stage (tile t) complete
    } else if (t + 1 < NK) {
      vmwait<NLD>();                     // tile t complete (t+1 still in flight)
    } else {
      vmwait<0>();
    }
    __builtin_amdgcn_s_barrier();        // buffer b ready on all waves
    bf16x8 af[FI], bfr[FJ];
#pragma unroll
    for (int i = 0; i < FI; ++i)
      af[i] = *(const bf16x8*)&As[b][(wm * WTM + i * 16 + l16) * 32 + (l4 ^ swz) * 8];
#pragma unroll
    for (int j = 0; j < FJ; ++j)
      bfr[j] = *(const bf16x8*)&Bs[b][(wn * WTN + j * 16 + l16) * 32 + (l4 ^ swz) * 8];
#pragma unroll
    for (int i = 0; i < FI; ++i)
#pragma unroll
      for (int j = 0; j < FJ; ++j)
        acc[i][j] = __builtin_amdgcn_mfma_f32_16x16x32_bf16(af[i], bfr[j], acc[i][j], 0, 0, 0);
    __builtin_amdgcn_s_barrier();        // all reads of b done before DMA overwrite
  }

#pragma unroll
  for (int i = 0; i < FI; ++i) {
    const long rr = bm + wm * WTM + i * 16 + l4 * 4;
#pragma unroll
    for (int j = 0; j < FJ; ++j) {
      const int cc = (int)bn + wn * WTN + j * 16 + l16;
#pragma unroll
      for (int r = 0; r < 4; ++r) {
        const long row = rr + r;
        const float v = acc[i][j][r];
        if (EPI == 0) {
          if (cc < INNER) C0[row * INNER + cc] = v;
          else            Cb[row * INNER + (cc - INNER)] = f2b(v);
        } else if (EPI == 1) {
          if (cc < 16) C0[row * 16 + cc] = v;
          else if (cc < 32) C1[row * 16 + (cc - 16)] = v;
          else if (cc < Nstore) {
            float sp = (v > 20.f) ? v : log1pf(__expf(v));
            C2[row * 1536 + (cc - 32)] = sp;
          }
        } else if (EPI == 2) {
          float g = b2f(Eb[row * INNER + cc]);
          float s = g / (1.f + __expf(-g));
          Cb[row * INNER + cc] = f2b(v * s);
        } else {
          C0[row * 768 + cc] = v + E0[row * 768 + cc];
        }
      }
    }
  }
}

// ---------------- depthwise causal conv(K=4) + SiLU ----------------
__global__ __launch_bounds__(256)
void conv_silu(const float* __restrict__ xu, const float* __restrict__ cw,
               float* __restrict__ uf, u16* __restrict__ ub) {
  const int c = blockIdx.x * 256 + threadIdx.x;
  const long m = blockIdx.y;
  const int t = (int)(m & (SEQ - 1));
  const float w0 = cw[c * 4 + 0], w1 = cw[c * 4 + 1], w2 = cw[c * 4 + 2], w3 = cw[c * 4 + 3];
  float acc = w3 * xu[m * 1536 + c];
  if (t >= 1) acc += w2 * xu[(m - 1) * 1536 + c];
  if (t >= 2) acc += w1 * xu[(m - 2) * 1536 + c];
  if (t >= 3) acc += w0 * xu[(m - 3) * 1536 + c];
  const float s = acc / (1.f + __expf(-acc));
  uf[m * 1536 + c] = s;
  ub[m * 1536 + c] = f2b(s);
}

// ---------------- scan phase A: per-chunk (P, Q) from h=0, 4 states/thread ------
__global__ __launch_bounds__(256)
void scan_phaseA(const float* __restrict__ dlt, const float* __restrict__ uf,
                 const float* __restrict__ Bm, const float* __restrict__ A_log,
                 float* __restrict__ P, float* __restrict__ Q) {
  const int tid = threadIdx.x;
  const int cl = tid >> 2;
  const int sg = tid & 3;
  const int c = blockIdx.x * 64 + cl;
  const int b = blockIdx.y;
  const int ch = blockIdx.z;
  float a2[4];
#pragma unroll
  for (int j = 0; j < 4; ++j) a2[j] = -__expf(A_log[sg * 4 + j]) * LOG2E;
  float h[4] = {0.f, 0.f, 0.f, 0.f};
  float sumd = 0.f;
  const long base = (long)b * SEQ + (long)ch * CHUNK;
  for (int t = 0; t < CHUNK; ++t) {
    const long m = base + t;
    const float d = dlt[m * 1536 + c];
    const float du = d * uf[m * 1536 + c];
    sumd += d;
    const f32x4 Bv = *(const f32x4*)&Bm[m * 16 + sg * 4];
#pragma unroll
    for (int j = 0; j < 4; ++j) {
      const float e = exp2f(a2[j] * d);
      h[j] = e * h[j] + du * Bv[j];
    }
  }
  const long sb = (((long)b * NCHUNK + ch) * NST + sg * 4) * 1536 + c;
#pragma unroll
  for (int j = 0; j < 4; ++j) {
    Q[sb + (long)j * 1536] = h[j];
    P[sb + (long)j * 1536] = exp2f(a2[j] * sumd);
  }
}

// ---------------- scan phase B: serial combine over chunks (hs aliases P) -------
__global__ __launch_bounds__(256)
void scan_phaseB(float* __restrict__ P, const float* __restrict__ Q) {
  const long g = (long)blockIdx.x * 256 + threadIdx.x;   // BATCH*NST*INNER
  const int c = (int)(g % 1536);
  const int n = (int)((g / 1536) % NST);
  const int b = (int)(g / (1536 * NST));
  float h = 0.f;
  for (int ch = 0; ch < NCHUNK; ++ch) {
    const long idx = (((long)b * NCHUNK + ch) * NST + n) * 1536 + c;
    const float p = P[idx];
    const float q = Q[idx];
    P[idx] = h;              // hs written in place of P (read-before-write)
    h = p * h + q;
  }
}

// ---------------- scan phase C: replay with true h_start, emit ys bf16 ----------
__global__ __launch_bounds__(256)
void scan_phaseC(const float* __restrict__ dlt, const float* __restrict__ uf,
                 const float* __restrict__ Bm, const float* __restrict__ Cm,
                 const float* __restrict__ A_log, const float* __restrict__ Dv,
                 const float* __restrict__ hs, u16* __restrict__ ys) {
  const int tid = threadIdx.x;
  const int cl = tid >> 2;
  const int sg = tid & 3;
  const int c = blockIdx.x * 64 + cl;
  const int b = blockIdx.y;
  const int ch = blockIdx.z;
  float a2[4];
#pragma unroll
  for (int j = 0; j < 4; ++j) a2[j] = -__expf(A_log[sg * 4 + j]) * LOG2E;
  float h[4];
  const long sb = (((long)b * NCHUNK + ch) * NST + sg * 4) * 1536 + c;
#pragma unroll
  for (int j = 0; j < 4; ++j) h[j] = hs[sb + (long)j * 1536];
  const float Dc = Dv[c];
  const long base = (long)b * SEQ + (long)ch * CHUNK;
  for (int t = 0; t < CHUNK; ++t) {
    const long m = base + t;
    const float d = dlt[m * 1536 + c];
    const float uu = uf[m * 1536 + c];
    const float du = d * uu;
    const f32x4 Bv = *(const f32x4*)&Bm[m * 16 + sg * 4];
    const f32x4 Cv = *(const f32x4*)&Cm[m * 16 + sg * 4];
    float y = (sg == 0) ? Dc * uu : 0.f;
#pragma unroll
    for (int j = 0; j < 4; ++j) {
      const float e = exp2f(a2[j] * d);
      h[j] = e * h[j] + du * Bv[j];
      y += h[j] * Cv[j];
    }
    y += __shfl_xor(y, 1);
    y += __shfl_xor(y, 2);
    if (sg == 0) ys[m * 1536 + c] = f2b(y);
  }
}

extern "C" void kernel_launch(void* const* d_in, const int* in_sizes, int n_in,
                              void* d_out, int out_size, void* d_ws, size_t ws_size,
                              hipStream_t stream) {
  const float* x     = (const float*)d_in[0];
  const float* nw    = (const float*)d_in[1];
  const float* nb    = (const float*)d_in[2];
  const float* W_in  = (const float*)d_in[3];
  const float* cw    = (const float*)d_in[4];
  const float* W_xp  = (const float*)d_in[5];
  const float* A_log = (const float*)d_in[6];
  const float* Dv    = (const float*)d_in[7];
  const float* W_so  = (const float*)d_in[8];
  const float* W_out = (const float*)d_in[9];
  float* out = (float*)d_out;

  char* w = (char*)d_ws;
  auto alloc = [&](size_t bytes) {
    char* p = w;
    w += (bytes + 255) & ~(size_t)255;
    return p;
  };
  u16*   xn    = (u16*)  alloc((size_t)MTOK * HID * 2);
  u16*   WtIn  = (u16*)  alloc((size_t)3072 * 768 * 2);
  float* xu    = (float*)alloc((size_t)MTOK * 1536 * 4);   // u half of xp, f32
  u16*   gb    = (u16*)  alloc((size_t)MTOK * 1536 * 2);   // gate half, bf16
  float* uf    = (float*)alloc((size_t)MTOK * 1536 * 4);
  u16*   ub    = (u16*)  alloc((size_t)MTOK * 1536 * 2);
  u16*   WtXp  = (u16*)  alloc((size_t)1664 * 1536 * 2);
  float* Bmv   = (float*)alloc((size_t)MTOK * 16 * 4);
  float* Cmv   = (float*)alloc((size_t)MTOK * 16 * 4);
  float* dlt   = (float*)alloc((size_t)MTOK * 1536 * 4);
  float* P     = (float*)alloc((size_t)BATCH * NCHUNK * NST * 1536 * 4);  // becomes hs
  float* Q     = (float*)alloc((size_t)BATCH * NCHUNK * NST * 1536 * 4);
  u16*   ys    = (u16*)  alloc((size_t)MTOK * 1536 * 2);
  u16*   WtSo  = (u16*)  alloc((size_t)1536 * 1536 * 2);
  u16*   zb    = (u16*)  alloc((size_t)MTOK * 1536 * 2);
  u16*   WtOut = (u16*)  alloc((size_t)768 * 1536 * 2);

  // merged LN + 4 weight transposes
  prologue<<<12352, 256, 0, stream>>>(x, nw, nb, xn,
                                      W_in, WtIn, W_xp, WtXp,
                                      W_so, WtSo, W_out, WtOut);

  // gemm0: 4096x3072, K=768  -> 128x64 tile, 48x32 = 1536 blocks
  gemm_bt<128, 64, 0><<<dim3(48, 32), 256, 0, stream>>>(xn, WtIn, xu, nullptr, nullptr, gb, nullptr, nullptr, 768, 3072);
  conv_silu<<<dim3(6, MTOK), 256, 0, stream>>>(xu, cw, uf, ub);
  // gemm1: 4096x1664, K=1536 -> 128x64 tile, 26x32 = 832 blocks
  gemm_bt<128, 64, 1><<<dim3(26, 32), 256, 0, stream>>>(ub, WtXp, Bmv, Cmv, dlt, nullptr, nullptr, nullptr, 1536, 1568);
  scan_phaseA<<<dim3(24, 2, NCHUNK), 256, 0, stream>>>(dlt, uf, Bmv, A_log, P, Q);
  scan_phaseB<<<192, 256, 0, stream>>>(P, Q);
  scan_phaseC<<<dim3(24, 2, NCHUNK), 256, 0, stream>>>(dlt, uf, Bmv, Cmv, A_log, Dv, P, ys);
  // gemm2: 4096x1536, K=1536 -> 128x64 tile, 24x32 = 768 blocks
  gemm_bt<128, 64, 2><<<dim3(24, 32), 256, 0, stream>>>(ys, WtSo, nullptr, nullptr, nullptr, zb, nullptr, gb, 1536, 1536);
  // gemm3: 4096x768,  K=1536 -> 64x64 tile, 12x64 = 768 blocks
  gemm_bt<64, 64, 3><<<dim3(12, 64), 256, 0, stream>>>(zb, WtOut, out, nullptr, nullptr, nullptr, x, nullptr, 1536, 768);
}

// Round 9
// 372.456 us; speedup vs baseline: 1.0675x; 1.0675x over previous
//
#include <hip/hip_runtime.h>
#include <cstdint>
#include <cmath>

#define HID 768
#define INNER 1536
#define NST 16
#define SEQ 2048
#define BATCH 2
#define MTOK 4096      // BATCH*SEQ
#define CHUNK 64
#define NCHUNK 32      // SEQ/CHUNK
#define LOG2E 1.44269504088896f

typedef unsigned short u16;
typedef __bf16 bf16x8 __attribute__((ext_vector_type(8)));
typedef float f32x4 __attribute__((ext_vector_type(4)));

__device__ __forceinline__ u16 f2b(float f) {
  union { float f; unsigned u; } a; a.f = f;
  unsigned r = a.u + 0x7FFFu + ((a.u >> 16) & 1u);
  return (u16)(r >> 16);
}

__device__ __forceinline__ float b2f(u16 h) {
  union { unsigned u; float f; } a; a.u = ((unsigned)h) << 16;
  return a.f;
}

__device__ __forceinline__ void gl2lds16(const u16* g, u16* l) {
  __builtin_amdgcn_global_load_lds(
      (const __attribute__((address_space(1))) void*)g,
      (__attribute__((address_space(3))) void*)l, 16, 0, 0);
}

template <int N>
__device__ __forceinline__ void vmwait() {
  if constexpr (N == 0)      asm volatile("s_waitcnt vmcnt(0)" ::: "memory");
  else if constexpr (N == 4) asm volatile("s_waitcnt vmcnt(4)" ::: "memory");
  else if constexpr (N == 6) asm volatile("s_waitcnt vmcnt(6)" ::: "memory");
  else static_assert(N == 0 || N == 4 || N == 6, "unsupported vmcnt");
}

// ---------------- merged prologue: LayerNorm + 4x transpose_cvt ----------------
// grid layout (1D):
//   [0, 4096)           LayerNorm rows
//   [4096, 6400)        W_in  768x3072 -> 3072x768   (96 x 24 blocks)
//   [6400, 8896)        W_xp  1536x1568 -> 1664x1536 (52 x 48 blocks, zero-pad)
//   [8896, 11200)       W_so  1536x1536 -> 1536x1536 (48 x 48 blocks)
//   [11200, 12352)      W_out 1536x768  -> 768x1536  (24 x 48 blocks)
__global__ __launch_bounds__(256)
void prologue(const float* __restrict__ x, const float* __restrict__ nw,
              const float* __restrict__ nb, u16* __restrict__ xn,
              const float* __restrict__ W0, u16* __restrict__ T0,
              const float* __restrict__ W1, u16* __restrict__ T1,
              const float* __restrict__ W2, u16* __restrict__ T2,
              const float* __restrict__ W3, u16* __restrict__ T3) {
  __shared__ float tb[32][33];
  __shared__ float r1[4], r2[4];
  const int tid = threadIdx.x;
  int bid = blockIdx.x;

  if (bid < MTOK) {
    // ---- LayerNorm + cast to bf16 ----
    const float* xr = x + (long)bid * HID;
    float v0 = xr[tid], v1 = xr[tid + 256], v2 = xr[tid + 512];
    float s1 = v0 + v1 + v2;
    float s2 = v0 * v0 + v1 * v1 + v2 * v2;
#pragma unroll
    for (int o = 32; o > 0; o >>= 1) { s1 += __shfl_down(s1, o); s2 += __shfl_down(s2, o); }
    if ((tid & 63) == 0) { r1[tid >> 6] = s1; r2[tid >> 6] = s2; }
    __syncthreads();
    s1 = r1[0] + r1[1] + r1[2] + r1[3];
    s2 = r2[0] + r2[1] + r2[2] + r2[3];
    const float mu = s1 * (1.f / HID);
    float var = s2 * (1.f / HID) - mu * mu;
    const float rs = rsqrtf(var + 1e-5f);
    xn[(long)bid * HID + tid]       = f2b((v0 - mu) * rs * nw[tid]       + nb[tid]);
    xn[(long)bid * HID + tid + 256] = f2b((v1 - mu) * rs * nw[tid + 256] + nb[tid + 256]);
    xn[(long)bid * HID + tid + 512] = f2b((v2 - mu) * rs * nw[tid + 512] + nb[tid + 512]);
    return;
  }

  // ---- transpose + cvt: fp32 W[K][N] -> bf16 Wt[Npad][K], zero pad ----
  bid -= MTOK;
  const float* W; u16* Wt; int K, N, nbx;
  if (bid < 2304)       {              W = W0; Wt = T0; K = 768;  N = 3072; nbx = 96; }
  else if (bid < 4800)  { bid -= 2304; W = W1; Wt = T1; K = 1536; N = 1568; nbx = 52; }
  else if (bid < 7104)  { bid -= 4800; W = W2; Wt = T2; K = 1536; N = 1536; nbx = 48; }
  else                  { bid -= 7104; W = W3; Wt = T3; K = 1536; N = 768;  nbx = 24; }
  const int tx = tid & 31, ty = tid >> 5;
  const int n0 = (bid % nbx) * 32, k0 = (bid / nbx) * 32;
#pragma unroll
  for (int r = 0; r < 4; ++r) {
    int kk = k0 + ty + r * 8;
    int nn = n0 + tx;
    tb[ty + r * 8][tx] = (nn < N) ? W[(long)kk * N + nn] : 0.f;
  }
  __syncthreads();
#pragma unroll
  for (int r = 0; r < 4; ++r) {
    int nn = n0 + ty + r * 8;
    int kk = k0 + tx;
    Wt[(long)nn * K + kk] = f2b(tb[tx][ty + r * 8]);
  }
}

// ---------------- GEMM: A[M][K] bf16 row-major, Bt[N][K] bf16, BMxBN tile ------
// 256 threads = 4 waves in 2x2; wave tile (BM/2)x(BN/2); BK in {32,64}.
// Double-buffered LDS, counted vmcnt, raw s_barrier, XOR-swizzled LDS chunks
// (both-sides: pre-swizzled global source, linear DMA dest, swizzled ds_read),
// bijective chunked XCD remap (m204).
// BK=32: rows/instr=64, chunk=tid&3, xor=(row>>1)&3, read xor=(l16>>1)&3  [R3-verified]
// BK=64: rows/instr=32, chunk=tid&7, xor=row&7,      read xor=l16&7       [R7-verified]
// EPI 0: cc<1536 -> C0[row*1536+cc]=v (u, f32); else Cb[row*1536+cc-1536]=bf16(v) (gate)
// EPI 1: cc<16 -> Bm, cc<32 -> Cm, cc<Nstore -> delta=softplus
// EPI 2: Cb = bf16(v * silu(gate)), gate = b2f(Eb[row*1536+cc])
// EPI 3: C0[row*768+cc] = v + E0[row*768+cc]
template <int BM, int BN, int BK, int EPI>
__global__ __launch_bounds__(256)
void gemm_bt(const u16* __restrict__ A, const u16* __restrict__ Bt,
             float* __restrict__ C0, float* __restrict__ C1, float* __restrict__ C2,
             u16* __restrict__ Cb, const float* __restrict__ E0,
             const u16* __restrict__ Eb, int K, int Nstore) {
  constexpr int WTM = BM / 2;        // wave tile M
  constexpr int WTN = BN / 2;        // wave tile N
  constexpr int FI = WTM / 16;       // A frags per wave
  constexpr int FJ = WTN / 16;       // B frags per wave
  constexpr int RPI = 2048 / BK;     // rows covered per stage instruction
  constexpr int NLD = BM / RPI + BN / RPI;  // DMA instrs per wave per K-step
  constexpr int KS = BK / 32;        // k-slices per K-step
  __shared__ u16 As[2][BM * BK];
  __shared__ u16 Bs[2][BN * BK];
  const int tid = threadIdx.x;
  const int lane = tid & 63;
  const int wave = tid >> 6;
  const int wm = wave >> 1, wn = wave & 1;
  const int l16 = lane & 15, l4 = lane >> 4;
  // read-side chunk xor per row (verified involutions)
  const int rsw = (BK == 64) ? (l16 & 7) : ((l16 >> 1) & 3);

  // bijective chunked XCD remap (m204)
  const int nwg = (int)(gridDim.x * gridDim.y);
  const int orig = (int)(blockIdx.y * gridDim.x + blockIdx.x);
  const int q = nwg >> 3, r = nwg & 7, xc = orig & 7;
  const int logical = (xc < r ? xc * (q + 1) : r * (q + 1) + (xc - r) * q) + (orig >> 3);
  const long bm = (long)(logical / (int)gridDim.x) * BM;
  const long bn = (long)(logical % (int)gridDim.x) * BN;

  f32x4 acc[FI][FJ] = {};

  // staging: row within RPI-row group; stored chunk = linear; fetch global
  // chunk xor'd by row so LDS[r][c] holds data chunk c^mask(r).
  const int sr = tid / (BK / 8);
  const int chn = tid & (BK / 8 - 1);
  const int smask = (BK == 64) ? (sr & 7) : ((sr >> 1) & 3);
  const int kg8 = ((chn ^ smask) * 8);

  auto stage = [&](int buf, int k0) {
#pragma unroll
    for (int qq = 0; qq < BM / RPI; ++qq)
      gl2lds16(A + (bm + qq * RPI + sr) * K + k0 + kg8, &As[buf][(qq * 256 + tid) * 8]);
#pragma unroll
    for (int qq = 0; qq < BN / RPI; ++qq)
      gl2lds16(Bt + (bn + qq * RPI + sr) * K + k0 + kg8, &Bs[buf][(qq * 256 + tid) * 8]);
  };

  const int NK = K / BK;
  stage(0, 0);
  int cur = 0;
  for (int t = 0; t < NK; ++t) {
    if (t + 1 < NK) {
      stage(cur ^ 1, (t + 1) * BK);  // next tile's loads stay in flight
      vmwait<NLD>();                 // only wait for CURRENT tile's loads
    } else {
      vmwait<0>();
    }
    __builtin_amdgcn_s_barrier();    // cur buffer ready on all waves
    bf16x8 af[FI][KS], bfr[FJ][KS];
#pragma unroll
    for (int i = 0; i < FI; ++i)
#pragma unroll
      for (int ks = 0; ks < KS; ++ks)
        af[i][ks] = *(const bf16x8*)&As[cur][(wm * WTM + i * 16 + l16) * BK +
                                            (((ks * 4 + l4) ^ rsw) * 8)];
#pragma unroll
    for (int j = 0; j < FJ; ++j)
#pragma unroll
      for (int ks = 0; ks < KS; ++ks)
        bfr[j][ks] = *(const bf16x8*)&Bs[cur][(wn * WTN + j * 16 + l16) * BK +
                                             (((ks * 4 + l4) ^ rsw) * 8)];
#pragma unroll
    for (int ks = 0; ks < KS; ++ks)
#pragma unroll
      for (int i = 0; i < FI; ++i)
#pragma unroll
        for (int j = 0; j < FJ; ++j)
          acc[i][j] = __builtin_amdgcn_mfma_f32_16x16x32_bf16(af[i][ks], bfr[j][ks], acc[i][j], 0, 0, 0);
    __builtin_amdgcn_s_barrier();    // all reads of cur done before overwrite
    cur ^= 1;
  }

#pragma unroll
  for (int i = 0; i < FI; ++i) {
    const long rr = bm + wm * WTM + i * 16 + l4 * 4;
#pragma unroll
    for (int j = 0; j < FJ; ++j) {
      const int cc = (int)bn + wn * WTN + j * 16 + l16;
#pragma unroll
      for (int r = 0; r < 4; ++r) {
        const long row = rr + r;
        const float v = acc[i][j][r];
        if (EPI == 0) {
          if (cc < INNER) C0[row * INNER + cc] = v;
          else            Cb[row * INNER + (cc - INNER)] = f2b(v);
        } else if (EPI == 1) {
          if (cc < 16) C0[row * 16 + cc] = v;
          else if (cc < 32) C1[row * 16 + (cc - 16)] = v;
          else if (cc < Nstore) {
            float sp = (v > 20.f) ? v : log1pf(__expf(v));
            C2[row * 1536 + (cc - 32)] = sp;
          }
        } else if (EPI == 2) {
          float g = b2f(Eb[row * INNER + cc]);
          float s = g / (1.f + __expf(-g));
          Cb[row * INNER + cc] = f2b(v * s);
        } else {
          C0[row * 768 + cc] = v + E0[row * 768 + cc];
        }
      }
    }
  }
}

// ---------------- depthwise causal conv(K=4) + SiLU ----------------
__global__ __launch_bounds__(256)
void conv_silu(const float* __restrict__ xu, const float* __restrict__ cw,
               float* __restrict__ uf, u16* __restrict__ ub) {
  const int c = blockIdx.x * 256 + threadIdx.x;
  const long m = blockIdx.y;
  const int t = (int)(m & (SEQ - 1));
  const float w0 = cw[c * 4 + 0], w1 = cw[c * 4 + 1], w2 = cw[c * 4 + 2], w3 = cw[c * 4 + 3];
  float acc = w3 * xu[m * 1536 + c];
  if (t >= 1) acc += w2 * xu[(m - 1) * 1536 + c];
  if (t >= 2) acc += w1 * xu[(m - 2) * 1536 + c];
  if (t >= 3) acc += w0 * xu[(m - 3) * 1536 + c];
  const float s = acc / (1.f + __expf(-acc));
  uf[m * 1536 + c] = s;
  ub[m * 1536 + c] = f2b(s);
}

// ---------------- scan phase A: per-chunk (P, Q) from h=0, 4 states/thread ------
__global__ __launch_bounds__(256)
void scan_phaseA(const float* __restrict__ dlt, const float* __restrict__ uf,
                 const float* __restrict__ Bm, const float* __restrict__ A_log,
                 float* __restrict__ P, float* __restrict__ Q) {
  const int tid = threadIdx.x;
  const int cl = tid >> 2;
  const int sg = tid & 3;
  const int c = blockIdx.x * 64 + cl;
  const int b = blockIdx.y;
  const int ch = blockIdx.z;
  float a2[4];
#pragma unroll
  for (int j = 0; j < 4; ++j) a2[j] = -__expf(A_log[sg * 4 + j]) * LOG2E;
  float h[4] = {0.f, 0.f, 0.f, 0.f};
  float sumd = 0.f;
  const long base = (long)b * SEQ + (long)ch * CHUNK;
  for (int t = 0; t < CHUNK; ++t) {
    const long m = base + t;
    const float d = dlt[m * 1536 + c];
    const float du = d * uf[m * 1536 + c];
    sumd += d;
    const f32x4 Bv = *(const f32x4*)&Bm[m * 16 + sg * 4];
#pragma unroll
    for (int j = 0; j < 4; ++j) {
      const float e = exp2f(a2[j] * d);
      h[j] = e * h[j] + du * Bv[j];
    }
  }
  const long sb = (((long)b * NCHUNK + ch) * NST + sg * 4) * 1536 + c;
#pragma unroll
  for (int j = 0; j < 4; ++j) {
    Q[sb + (long)j * 1536] = h[j];
    P[sb + (long)j * 1536] = exp2f(a2[j] * sumd);
  }
}

// ---------------- scan phase B: serial combine over chunks (hs aliases P) -------
__global__ __launch_bounds__(256)
void scan_phaseB(float* __restrict__ P, const float* __restrict__ Q) {
  const long g = (long)blockIdx.x * 256 + threadIdx.x;   // BATCH*NST*INNER
  const int c = (int)(g % 1536);
  const int n = (int)((g / 1536) % NST);
  const int b = (int)(g / (1536 * NST));
  float h = 0.f;
  for (int ch = 0; ch < NCHUNK; ++ch) {
    const long idx = (((long)b * NCHUNK + ch) * NST + n) * 1536 + c;
    const float p = P[idx];
    const float q = Q[idx];
    P[idx] = h;              // hs written in place of P (read-before-write)
    h = p * h + q;
  }
}

// ---------------- scan phase C: replay with true h_start, emit ys bf16 ----------
__global__ __launch_bounds__(256)
void scan_phaseC(const float* __restrict__ dlt, const float* __restrict__ uf,
                 const float* __restrict__ Bm, const float* __restrict__ Cm,
                 const float* __restrict__ A_log, const float* __restrict__ Dv,
                 const float* __restrict__ hs, u16* __restrict__ ys) {
  const int tid = threadIdx.x;
  const int cl = tid >> 2;
  const int sg = tid & 3;
  const int c = blockIdx.x * 64 + cl;
  const int b = blockIdx.y;
  const int ch = blockIdx.z;
  float a2[4];
#pragma unroll
  for (int j = 0; j < 4; ++j) a2[j] = -__expf(A_log[sg * 4 + j]) * LOG2E;
  float h[4];
  const long sb = (((long)b * NCHUNK + ch) * NST + sg * 4) * 1536 + c;
#pragma unroll
  for (int j = 0; j < 4; ++j) h[j] = hs[sb + (long)j * 1536];
  const float Dc = Dv[c];
  const long base = (long)b * SEQ + (long)ch * CHUNK;
  for (int t = 0; t < CHUNK; ++t) {
    const long m = base + t;
    const float d = dlt[m * 1536 + c];
    const float uu = uf[m * 1536 + c];
    const float du = d * uu;
    const f32x4 Bv = *(const f32x4*)&Bm[m * 16 + sg * 4];
    const f32x4 Cv = *(const f32x4*)&Cm[m * 16 + sg * 4];
    float y = (sg == 0) ? Dc * uu : 0.f;
#pragma unroll
    for (int j = 0; j < 4; ++j) {
      const float e = exp2f(a2[j] * d);
      h[j] = e * h[j] + du * Bv[j];
      y += h[j] * Cv[j];
    }
    y += __shfl_xor(y, 1);
    y += __shfl_xor(y, 2);
    if (sg == 0) ys[m * 1536 + c] = f2b(y);
  }
}

extern "C" void kernel_launch(void* const* d_in, const int* in_sizes, int n_in,
                              void* d_out, int out_size, void* d_ws, size_t ws_size,
                              hipStream_t stream) {
  const float* x     = (const float*)d_in[0];
  const float* nw    = (const float*)d_in[1];
  const float* nb    = (const float*)d_in[2];
  const float* W_in  = (const float*)d_in[3];
  const float* cw    = (const float*)d_in[4];
  const float* W_xp  = (const float*)d_in[5];
  const float* A_log = (const float*)d_in[6];
  const float* Dv    = (const float*)d_in[7];
  const float* W_so  = (const float*)d_in[8];
  const float* W_out = (const float*)d_in[9];
  float* out = (float*)d_out;

  char* w = (char*)d_ws;
  auto alloc = [&](size_t bytes) {
    char* p = w;
    w += (bytes + 255) & ~(size_t)255;
    return p;
  };
  u16*   xn    = (u16*)  alloc((size_t)MTOK * HID * 2);
  u16*   WtIn  = (u16*)  alloc((size_t)3072 * 768 * 2);
  float* xu    = (float*)alloc((size_t)MTOK * 1536 * 4);   // u half of xp, f32
  u16*   gb    = (u16*)  alloc((size_t)MTOK * 1536 * 2);   // gate half, bf16
  float* uf    = (float*)alloc((size_t)MTOK * 1536 * 4);
  u16*   ub    = (u16*)  alloc((size_t)MTOK * 1536 * 2);
  u16*   WtXp  = (u16*)  alloc((size_t)1664 * 1536 * 2);
  float* Bmv   = (float*)alloc((size_t)MTOK * 16 * 4);
  float* Cmv   = (float*)alloc((size_t)MTOK * 16 * 4);
  float* dlt   = (float*)alloc((size_t)MTOK * 1536 * 4);
  float* P     = (float*)alloc((size_t)BATCH * NCHUNK * NST * 1536 * 4);  // becomes hs
  float* Q     = (float*)alloc((size_t)BATCH * NCHUNK * NST * 1536 * 4);
  u16*   ys    = (u16*)  alloc((size_t)MTOK * 1536 * 2);
  u16*   WtSo  = (u16*)  alloc((size_t)1536 * 1536 * 2);
  u16*   zb    = (u16*)  alloc((size_t)MTOK * 1536 * 2);
  u16*   WtOut = (u16*)  alloc((size_t)768 * 1536 * 2);

  // merged LN + 4 weight transposes
  prologue<<<12352, 256, 0, stream>>>(x, nw, nb, xn,
                                      W_in, WtIn, W_xp, WtXp,
                                      W_so, WtSo, W_out, WtOut);

  // gemm0: 4096x3072, K=768  -> 128x128 tile BK=32, 24x32 = 768 blocks (bytes 453->302 MB)
  gemm_bt<128, 128, 32, 0><<<dim3(24, 32), 256, 0, stream>>>(xn, WtIn, xu, nullptr, nullptr, gb, nullptr, nullptr, 768, 3072);
  conv_silu<<<dim3(6, MTOK), 256, 0, stream>>>(xu, cw, uf, ub);
  // gemm1: 4096x1664, K=1536 -> 128x64 tile BK=64, 26x32 = 832 blocks (CONTROL)
  gemm_bt<128, 64, 64, 1><<<dim3(26, 32), 256, 0, stream>>>(ub, WtXp, Bmv, Cmv, dlt, nullptr, nullptr, nullptr, 1536, 1568);
  scan_phaseA<<<dim3(24, 2, NCHUNK), 256, 0, stream>>>(dlt, uf, Bmv, A_log, P, Q);
  scan_phaseB<<<192, 256, 0, stream>>>(P, Q);
  scan_phaseC<<<dim3(24, 2, NCHUNK), 256, 0, stream>>>(dlt, uf, Bmv, Cmv, A_log, Dv, P, ys);
  // gemm2: 4096x1536, K=1536 -> 128x64 tile BK=64, 24x32 = 768 blocks (CONTROL)
  gemm_bt<128, 64, 64, 2><<<dim3(24, 32), 256, 0, stream>>>(ys, WtSo, nullptr, nullptr, nullptr, zb, nullptr, gb, 1536, 1536);
  // gemm3: 4096x768,  K=1536 -> 128x64 tile BK=64, 12x32 = 384 blocks (bytes 302->227 MB)
  gemm_bt<128, 64, 64, 3><<<dim3(12, 32), 256, 0, stream>>>(zb, WtOut, out, nullptr, nullptr, nullptr, x, nullptr, 1536, 768);
}

// Round 11
// 361.312 us; speedup vs baseline: 1.1005x; 1.0308x over previous
//
#include <hip/hip_runtime.h>
#include <cstdint>
#include <cmath>

#define HID 768
#define INNER 1536
#define NST 16
#define SEQ 2048
#define BATCH 2
#define MTOK 4096      // BATCH*SEQ
#define CHUNK 64
#define NCHUNK 32      // SEQ/CHUNK
#define LOG2E 1.44269504088896f

typedef unsigned short u16;
typedef __bf16 bf16x8 __attribute__((ext_vector_type(8)));
typedef float f32x4 __attribute__((ext_vector_type(4)));

__device__ __forceinline__ u16 f2b(float f) {
  union { float f; unsigned u; } a; a.f = f;
  unsigned r = a.u + 0x7FFFu + ((a.u >> 16) & 1u);
  return (u16)(r >> 16);
}

__device__ __forceinline__ float b2f(u16 h) {
  union { unsigned u; float f; } a; a.u = ((unsigned)h) << 16;
  return a.f;
}

__device__ __forceinline__ void gl2lds16(const u16* g, u16* l) {
  __builtin_amdgcn_global_load_lds(
      (const __attribute__((address_space(1))) void*)g,
      (__attribute__((address_space(3))) void*)l, 16, 0, 0);
}

template <int N>
__device__ __forceinline__ void vmwait() {
  if constexpr (N == 0)      asm volatile("s_waitcnt vmcnt(0)" ::: "memory");
  else if constexpr (N == 4) asm volatile("s_waitcnt vmcnt(4)" ::: "memory");
  else if constexpr (N == 6) asm volatile("s_waitcnt vmcnt(6)" ::: "memory");
  else static_assert(N == 0 || N == 4 || N == 6, "unsupported vmcnt");
}

// ---------------- merged prologue: LayerNorm + 4x transpose_cvt ----------------
// grid layout (1D):
//   [0, 4096)           LayerNorm rows
//   [4096, 6400)        W_in  768x3072 -> 3072x768   (96 x 24 blocks)
//   [6400, 8896)        W_xp  1536x1568 -> 1664x1536 (52 x 48 blocks, zero-pad)
//   [8896, 11200)       W_so  1536x1536 -> 1536x1536 (48 x 48 blocks)
//   [11200, 12352)      W_out 1536x768  -> 768x1536  (24 x 48 blocks)
__global__ __launch_bounds__(256)
void prologue(const float* __restrict__ x, const float* __restrict__ nw,
              const float* __restrict__ nb, u16* __restrict__ xn,
              const float* __restrict__ W0, u16* __restrict__ T0,
              const float* __restrict__ W1, u16* __restrict__ T1,
              const float* __restrict__ W2, u16* __restrict__ T2,
              const float* __restrict__ W3, u16* __restrict__ T3) {
  __shared__ float tb[32][33];
  __shared__ float r1[4], r2[4];
  const int tid = threadIdx.x;
  int bid = blockIdx.x;

  if (bid < MTOK) {
    // ---- LayerNorm + cast to bf16 ----
    const float* xr = x + (long)bid * HID;
    float v0 = xr[tid], v1 = xr[tid + 256], v2 = xr[tid + 512];
    float s1 = v0 + v1 + v2;
    float s2 = v0 * v0 + v1 * v1 + v2 * v2;
#pragma unroll
    for (int o = 32; o > 0; o >>= 1) { s1 += __shfl_down(s1, o); s2 += __shfl_down(s2, o); }
    if ((tid & 63) == 0) { r1[tid >> 6] = s1; r2[tid >> 6] = s2; }
    __syncthreads();
    s1 = r1[0] + r1[1] + r1[2] + r1[3];
    s2 = r2[0] + r2[1] + r2[2] + r2[3];
    const float mu = s1 * (1.f / HID);
    float var = s2 * (1.f / HID) - mu * mu;
    const float rs = rsqrtf(var + 1e-5f);
    xn[(long)bid * HID + tid]       = f2b((v0 - mu) * rs * nw[tid]       + nb[tid]);
    xn[(long)bid * HID + tid + 256] = f2b((v1 - mu) * rs * nw[tid + 256] + nb[tid + 256]);
    xn[(long)bid * HID + tid + 512] = f2b((v2 - mu) * rs * nw[tid + 512] + nb[tid + 512]);
    return;
  }

  // ---- transpose + cvt: fp32 W[K][N] -> bf16 Wt[Npad][K], zero pad ----
  bid -= MTOK;
  const float* W; u16* Wt; int K, N, nbx;
  if (bid < 2304)       {              W = W0; Wt = T0; K = 768;  N = 3072; nbx = 96; }
  else if (bid < 4800)  { bid -= 2304; W = W1; Wt = T1; K = 1536; N = 1568; nbx = 52; }
  else if (bid < 7104)  { bid -= 4800; W = W2; Wt = T2; K = 1536; N = 1536; nbx = 48; }
  else                  { bid -= 7104; W = W3; Wt = T3; K = 1536; N = 768;  nbx = 24; }
  const int tx = tid & 31, ty = tid >> 5;
  const int n0 = (bid % nbx) * 32, k0 = (bid / nbx) * 32;
#pragma unroll
  for (int r = 0; r < 4; ++r) {
    int kk = k0 + ty + r * 8;
    int nn = n0 + tx;
    tb[ty + r * 8][tx] = (nn < N) ? W[(long)kk * N + nn] : 0.f;
  }
  __syncthreads();
#pragma unroll
  for (int r = 0; r < 4; ++r) {
    int nn = n0 + ty + r * 8;
    int kk = k0 + tx;
    Wt[(long)nn * K + kk] = f2b(tb[tx][ty + r * 8]);
  }
}

// ---------------- GEMM: A[M][K] bf16 row-major, Bt[N][K] bf16, BMxBN tile ------
// 256 threads = 4 waves in 2x2; wave tile (BM/2)x(BN/2); BK in {32,64}.
// Double-buffered LDS, counted vmcnt, raw s_barrier, XOR-swizzled LDS chunks
// (both-sides: pre-swizzled global source, linear DMA dest, swizzled ds_read),
// bijective chunked XCD remap (m204).
// BK=32: rows/instr=64, chunk=tid&3, xor=(row>>1)&3, read xor=(l16>>1)&3  [R3-verified]
// BK=64: rows/instr=32, chunk=tid&7, xor=row&7,      read xor=l16&7       [R7-verified]
// EPI 0: cc<1536 -> Cb2[row*1536+cc]=bf16(v) (u half); else Cb[row*1536+cc-1536]=bf16(v) (gate)
// EPI 1: cc<16 -> Bm, cc<32 -> Cm, cc<Nstore -> delta=softplus
// EPI 2: Cb = bf16(v * silu(gate)), gate = b2f(Eb[row*1536+cc])
// EPI 3: C0[row*768+cc] = v + E0[row*768+cc]
template <int BM, int BN, int BK, int EPI>
__global__ __launch_bounds__(256)
void gemm_bt(const u16* __restrict__ A, const u16* __restrict__ Bt,
             float* __restrict__ C0, float* __restrict__ C1, float* __restrict__ C2,
             u16* __restrict__ Cb, u16* __restrict__ Cb2,
             const float* __restrict__ E0, const u16* __restrict__ Eb,
             int K, int Nstore) {
  constexpr int WTM = BM / 2;        // wave tile M
  constexpr int WTN = BN / 2;        // wave tile N
  constexpr int FI = WTM / 16;       // A frags per wave
  constexpr int FJ = WTN / 16;       // B frags per wave
  constexpr int RPI = 2048 / BK;     // rows covered per stage instruction
  constexpr int NLD = BM / RPI + BN / RPI;  // DMA instrs per wave per K-step
  constexpr int KS = BK / 32;        // k-slices per K-step
  __shared__ u16 As[2][BM * BK];
  __shared__ u16 Bs[2][BN * BK];
  const int tid = threadIdx.x;
  const int lane = tid & 63;
  const int wave = tid >> 6;
  const int wm = wave >> 1, wn = wave & 1;
  const int l16 = lane & 15, l4 = lane >> 4;
  // read-side chunk xor per row (verified involutions)
  const int rsw = (BK == 64) ? (l16 & 7) : ((l16 >> 1) & 3);

  // bijective chunked XCD remap (m204)
  const int nwg = (int)(gridDim.x * gridDim.y);
  const int orig = (int)(blockIdx.y * gridDim.x + blockIdx.x);
  const int q = nwg >> 3, r = nwg & 7, xc = orig & 7;
  const int logical = (xc < r ? xc * (q + 1) : r * (q + 1) + (xc - r) * q) + (orig >> 3);
  const long bm = (long)(logical / (int)gridDim.x) * BM;
  const long bn = (long)(logical % (int)gridDim.x) * BN;

  f32x4 acc[FI][FJ] = {};

  // staging: row within RPI-row group; stored chunk = linear; fetch global
  // chunk xor'd by row so LDS[r][c] holds data chunk c^mask(r).
  const int sr = tid / (BK / 8);
  const int chn = tid & (BK / 8 - 1);
  const int smask = (BK == 64) ? (sr & 7) : ((sr >> 1) & 3);
  const int kg8 = ((chn ^ smask) * 8);

  auto stage = [&](int buf, int k0) {
#pragma unroll
    for (int qq = 0; qq < BM / RPI; ++qq)
      gl2lds16(A + (bm + qq * RPI + sr) * K + k0 + kg8, &As[buf][(qq * 256 + tid) * 8]);
#pragma unroll
    for (int qq = 0; qq < BN / RPI; ++qq)
      gl2lds16(Bt + (bn + qq * RPI + sr) * K + k0 + kg8, &Bs[buf][(qq * 256 + tid) * 8]);
  };

  const int NK = K / BK;
  stage(0, 0);
  int cur = 0;
  for (int t = 0; t < NK; ++t) {
    if (t + 1 < NK) {
      stage(cur ^ 1, (t + 1) * BK);  // next tile's loads stay in flight
      vmwait<NLD>();                 // only wait for CURRENT tile's loads
    } else {
      vmwait<0>();
    }
    __builtin_amdgcn_s_barrier();    // cur buffer ready on all waves
    bf16x8 af[FI][KS], bfr[FJ][KS];
#pragma unroll
    for (int i = 0; i < FI; ++i)
#pragma unroll
      for (int ks = 0; ks < KS; ++ks)
        af[i][ks] = *(const bf16x8*)&As[cur][(wm * WTM + i * 16 + l16) * BK +
                                            (((ks * 4 + l4) ^ rsw) * 8)];
#pragma unroll
    for (int j = 0; j < FJ; ++j)
#pragma unroll
      for (int ks = 0; ks < KS; ++ks)
        bfr[j][ks] = *(const bf16x8*)&Bs[cur][(wn * WTN + j * 16 + l16) * BK +
                                             (((ks * 4 + l4) ^ rsw) * 8)];
#pragma unroll
    for (int ks = 0; ks < KS; ++ks)
#pragma unroll
      for (int i = 0; i < FI; ++i)
#pragma unroll
        for (int j = 0; j < FJ; ++j)
          acc[i][j] = __builtin_amdgcn_mfma_f32_16x16x32_bf16(af[i][ks], bfr[j][ks], acc[i][j], 0, 0, 0);
    __builtin_amdgcn_s_barrier();    // all reads of cur done before overwrite
    cur ^= 1;
  }

#pragma unroll
  for (int i = 0; i < FI; ++i) {
    const long rr = bm + wm * WTM + i * 16 + l4 * 4;
#pragma unroll
    for (int j = 0; j < FJ; ++j) {
      const int cc = (int)bn + wn * WTN + j * 16 + l16;
#pragma unroll
      for (int r = 0; r < 4; ++r) {
        const long row = rr + r;
        const float v = acc[i][j][r];
        if (EPI == 0) {
          if (cc < INNER) Cb2[row * INNER + cc] = f2b(v);
          else            Cb[row * INNER + (cc - INNER)] = f2b(v);
        } else if (EPI == 1) {
          if (cc < 16) C0[row * 16 + cc] = v;
          else if (cc < 32) C1[row * 16 + (cc - 16)] = v;
          else if (cc < Nstore) {
            float sp = (v > 20.f) ? v : log1pf(__expf(v));
            C2[row * 1536 + (cc - 32)] = sp;
          }
        } else if (EPI == 2) {
          float g = b2f(Eb[row * INNER + cc]);
          float s = g / (1.f + __expf(-g));
          Cb[row * INNER + cc] = f2b(v * s);
        } else {
          C0[row * 768 + cc] = v + E0[row * 768 + cc];
        }
      }
    }
  }
}

// ---------------- depthwise causal conv(K=4) + SiLU (bf16 in, bf16 out) --------
__global__ __launch_bounds__(256)
void conv_silu(const u16* __restrict__ ubr, const float* __restrict__ cw,
               u16* __restrict__ uf) {
  const int c = blockIdx.x * 256 + threadIdx.x;
  const long m = blockIdx.y;
  const int t = (int)(m & (SEQ - 1));
  const f32x4 wv = *(const f32x4*)&cw[c * 4];
  float acc = wv[3] * b2f(ubr[m * 1536 + c]);
  if (t >= 1) acc += wv[2] * b2f(ubr[(m - 1) * 1536 + c]);
  if (t >= 2) acc += wv[1] * b2f(ubr[(m - 2) * 1536 + c]);
  if (t >= 3) acc += wv[0] * b2f(ubr[(m - 3) * 1536 + c]);
  const float s = acc / (1.f + __expf(-acc));
  uf[m * 1536 + c] = f2b(s);
}

// ---------------- scan phase A: per-chunk (P, Q) from h=0, 4 states/thread ------
__global__ __launch_bounds__(256)
void scan_phaseA(const float* __restrict__ dlt, const u16* __restrict__ uf,
                 const float* __restrict__ Bm, const float* __restrict__ A_log,
                 float* __restrict__ P, float* __restrict__ Q) {
  const int tid = threadIdx.x;
  const int cl = tid >> 2;
  const int sg = tid & 3;
  const int c = blockIdx.x * 64 + cl;
  const int b = blockIdx.y;
  const int ch = blockIdx.z;
  float a2[4];
#pragma unroll
  for (int j = 0; j < 4; ++j) a2[j] = -__expf(A_log[sg * 4 + j]) * LOG2E;
  float h[4] = {0.f, 0.f, 0.f, 0.f};
  float sumd = 0.f;
  const long base = (long)b * SEQ + (long)ch * CHUNK;
  for (int t = 0; t < CHUNK; ++t) {
    const long m = base + t;
    const float d = dlt[m * 1536 + c];
    const float du = d * b2f(uf[m * 1536 + c]);
    sumd += d;
    const f32x4 Bv = *(const f32x4*)&Bm[m * 16 + sg * 4];
#pragma unroll
    for (int j = 0; j < 4; ++j) {
      const float e = exp2f(a2[j] * d);
      h[j] = e * h[j] + du * Bv[j];
    }
  }
  const long sb = (((long)b * NCHUNK + ch) * NST + sg * 4) * 1536 + c;
#pragma unroll
  for (int j = 0; j < 4; ++j) {
    Q[sb + (long)j * 1536] = h[j];
    P[sb + (long)j * 1536] = exp2f(a2[j] * sumd);
  }
}

// ---------------- scan phase B: serial combine over chunks (hs aliases P) -------
__global__ __launch_bounds__(256)
void scan_phaseB(float* __restrict__ P, const float* __restrict__ Q) {
  const long g = (long)blockIdx.x * 256 + threadIdx.x;   // BATCH*NST*INNER
  const int c = (int)(g % 1536);
  const int n = (int)((g / 1536) % NST);
  const int b = (int)(g / (1536 * NST));
  float h = 0.f;
  for (int ch = 0; ch < NCHUNK; ++ch) {
    const long idx = (((long)b * NCHUNK + ch) * NST + n) * 1536 + c;
    const float p = P[idx];
    const float q = Q[idx];
    P[idx] = h;              // hs written in place of P (read-before-write)
    h = p * h + q;
  }
}

// ---------------- scan phase C: replay with true h_start, emit ys bf16 ----------
__global__ __launch_bounds__(256)
void scan_phaseC(const float* __restrict__ dlt, const u16* __restrict__ uf,
                 const float* __restrict__ Bm, const float* __restrict__ Cm,
                 const float* __restrict__ A_log, const float* __restrict__ Dv,
                 const float* __restrict__ hs, u16* __restrict__ ys) {
  const int tid = threadIdx.x;
  const int cl = tid >> 2;
  const int sg = tid & 3;
  const int c = blockIdx.x * 64 + cl;
  const int b = blockIdx.y;
  const int ch = blockIdx.z;
  float a2[4];
#pragma unroll
  for (int j = 0; j < 4; ++j) a2[j] = -__expf(A_log[sg * 4 + j]) * LOG2E;
  float h[4];
  const long sb = (((long)b * NCHUNK + ch) * NST + sg * 4) * 1536 + c;
#pragma unroll
  for (int j = 0; j < 4; ++j) h[j] = hs[sb + (long)j * 1536];
  const float Dc = Dv[c];
  const long base = (long)b * SEQ + (long)ch * CHUNK;
  for (int t = 0; t < CHUNK; ++t) {
    const long m = base + t;
    const float d = dlt[m * 1536 + c];
    const float uu = b2f(uf[m * 1536 + c]);
    const float du = d * uu;
    const f32x4 Bv = *(const f32x4*)&Bm[m * 16 + sg * 4];
    const f32x4 Cv = *(const f32x4*)&Cm[m * 16 + sg * 4];
    float y = (sg == 0) ? Dc * uu : 0.f;
#pragma unroll
    for (int j = 0; j < 4; ++j) {
      const float e = exp2f(a2[j] * d);
      h[j] = e * h[j] + du * Bv[j];
      y += h[j] * Cv[j];
    }
    y += __shfl_xor(y, 1);
    y += __shfl_xor(y, 2);
    if (sg == 0) ys[m * 1536 + c] = f2b(y);
  }
}

extern "C" void kernel_launch(void* const* d_in, const int* in_sizes, int n_in,
                              void* d_out, int out_size, void* d_ws, size_t ws_size,
                              hipStream_t stream) {
  const float* x     = (const float*)d_in[0];
  const float* nw    = (const float*)d_in[1];
  const float* nb    = (const float*)d_in[2];
  const float* W_in  = (const float*)d_in[3];
  const float* cw    = (const float*)d_in[4];
  const float* W_xp  = (const float*)d_in[5];
  const float* A_log = (const float*)d_in[6];
  const float* Dv    = (const float*)d_in[7];
  const float* W_so  = (const float*)d_in[8];
  const float* W_out = (const float*)d_in[9];
  float* out = (float*)d_out;

  char* w = (char*)d_ws;
  auto alloc = [&](size_t bytes) {
    char* p = w;
    w += (bytes + 255) & ~(size_t)255;
    return p;
  };
  u16*   xn    = (u16*)  alloc((size_t)MTOK * HID * 2);
  u16*   WtIn  = (u16*)  alloc((size_t)3072 * 768 * 2);
  u16*   ubr   = (u16*)  alloc((size_t)MTOK * 1536 * 2);   // u half pre-conv, bf16
  u16*   gb    = (u16*)  alloc((size_t)MTOK * 1536 * 2);   // gate half, bf16
  u16*   uf    = (u16*)  alloc((size_t)MTOK * 1536 * 2);   // conv+silu output, bf16
  u16*   WtXp  = (u16*)  alloc((size_t)1664 * 1536 * 2);
  float* Bmv   = (float*)alloc((size_t)MTOK * 16 * 4);
  float* Cmv   = (float*)alloc((size_t)MTOK * 16 * 4);
  float* dlt   = (float*)alloc((size_t)MTOK * 1536 * 4);
  float* P     = (float*)alloc((size_t)BATCH * NCHUNK * NST * 1536 * 4);  // becomes hs
  float* Q     = (float*)alloc((size_t)BATCH * NCHUNK * NST * 1536 * 4);
  u16*   ys    = (u16*)  alloc((size_t)MTOK * 1536 * 2);
  u16*   WtSo  = (u16*)  alloc((size_t)1536 * 1536 * 2);
  u16*   zb    = (u16*)  alloc((size_t)MTOK * 1536 * 2);
  u16*   WtOut = (u16*)  alloc((size_t)768 * 1536 * 2);

  // merged LN + 4 weight transposes
  prologue<<<12352, 256, 0, stream>>>(x, nw, nb, xn,
                                      W_in, WtIn, W_xp, WtXp,
                                      W_so, WtSo, W_out, WtOut);

  // gemm0: 4096x3072, K=768  -> 128x64 tile BK=64, 48x32 = 1536 blocks
  gemm_bt<128, 64, 64, 0><<<dim3(48, 32), 256, 0, stream>>>(xn, WtIn, nullptr, nullptr, nullptr, gb, ubr, nullptr, nullptr, 768, 3072);
  conv_silu<<<dim3(6, MTOK), 256, 0, stream>>>(ubr, cw, uf);
  // gemm1: 4096x1664, K=1536 -> 128x64 tile BK=64, 26x32 = 832 blocks
  gemm_bt<128, 64, 64, 1><<<dim3(26, 32), 256, 0, stream>>>(uf, WtXp, Bmv, Cmv, dlt, nullptr, nullptr, nullptr, nullptr, 1536, 1568);
  scan_phaseA<<<dim3(24, 2, NCHUNK), 256, 0, stream>>>(dlt, uf, Bmv, A_log, P, Q);
  scan_phaseB<<<192, 256, 0, stream>>>(P, Q);
  scan_phaseC<<<dim3(24, 2, NCHUNK), 256, 0, stream>>>(dlt, uf, Bmv, Cmv, A_log, Dv, P, ys);
  // gemm2: 4096x1536, K=1536 -> 128x64 tile BK=64, 24x32 = 768 blocks
  gemm_bt<128, 64, 64, 2><<<dim3(24, 32), 256, 0, stream>>>(ys, WtSo, nullptr, nullptr, nullptr, zb, nullptr, nullptr, gb, 1536, 1536);
  // gemm3: 4096x768,  K=1536 -> 64x64 tile BK=64, 12x64 = 768 blocks
  gemm_bt<64, 64, 64, 3><<<dim3(12, 64), 256, 0, stream>>>(zb, WtOut, out, nullptr, nullptr, nullptr, nullptr, x, nullptr, 1536, 768);
}

// Round 12
// 350.654 us; speedup vs baseline: 1.1339x; 1.0304x over previous
//
#include <hip/hip_runtime.h>
#include <cstdint>
#include <cmath>

#define HID 768
#define INNER 1536
#define NST 16
#define SEQ 2048
#define BATCH 2
#define MTOK 4096      // BATCH*SEQ
#define CHUNK 64
#define NCHUNK 32      // SEQ/CHUNK
#define LOG2E 1.44269504088896f

typedef unsigned short u16;
typedef __bf16 bf16x8 __attribute__((ext_vector_type(8)));
typedef float f32x4 __attribute__((ext_vector_type(4)));

__device__ __forceinline__ u16 f2b(float f) {
  union { float f; unsigned u; } a; a.f = f;
  unsigned r = a.u + 0x7FFFu + ((a.u >> 16) & 1u);
  return (u16)(r >> 16);
}

__device__ __forceinline__ float b2f(u16 h) {
  union { unsigned u; float f; } a; a.u = ((unsigned)h) << 16;
  return a.f;
}

__device__ __forceinline__ void gl2lds16(const u16* g, u16* l) {
  __builtin_amdgcn_global_load_lds(
      (const __attribute__((address_space(1))) void*)g,
      (__attribute__((address_space(3))) void*)l, 16, 0, 0);
}

template <int N>
__device__ __forceinline__ void vmwait() {
  if constexpr (N == 0)      asm volatile("s_waitcnt vmcnt(0)" ::: "memory");
  else if constexpr (N == 2) asm volatile("s_waitcnt vmcnt(2)" ::: "memory");
  else if constexpr (N == 3) asm volatile("s_waitcnt vmcnt(3)" ::: "memory");
  else if constexpr (N == 4) asm volatile("s_waitcnt vmcnt(4)" ::: "memory");
  else if constexpr (N == 6) asm volatile("s_waitcnt vmcnt(6)" ::: "memory");
  else static_assert(N == 0, "unsupported vmcnt");
}

// ---------------- merged prologue: LayerNorm + 4x transpose_cvt ----------------
// grid layout (1D):
//   [0, 4096)           LayerNorm rows
//   [4096, 6400)        W_in  768x3072 -> 3072x768   (96 x 24 blocks)
//   [6400, 8896)        W_xp  1536x1568 -> 1664x1536 (52 x 48 blocks, zero-pad)
//   [8896, 11200)       W_so  1536x1536 -> 1536x1536 (48 x 48 blocks)
//   [11200, 12352)      W_out 1536x768  -> 768x1536  (24 x 48 blocks)
__global__ __launch_bounds__(256)
void prologue(const float* __restrict__ x, const float* __restrict__ nw,
              const float* __restrict__ nb, u16* __restrict__ xn,
              const float* __restrict__ W0, u16* __restrict__ T0,
              const float* __restrict__ W1, u16* __restrict__ T1,
              const float* __restrict__ W2, u16* __restrict__ T2,
              const float* __restrict__ W3, u16* __restrict__ T3) {
  __shared__ float tb[32][33];
  __shared__ float r1[4], r2[4];
  const int tid = threadIdx.x;
  int bid = blockIdx.x;

  if (bid < MTOK) {
    // ---- LayerNorm + cast to bf16 ----
    const float* xr = x + (long)bid * HID;
    float v0 = xr[tid], v1 = xr[tid + 256], v2 = xr[tid + 512];
    float s1 = v0 + v1 + v2;
    float s2 = v0 * v0 + v1 * v1 + v2 * v2;
#pragma unroll
    for (int o = 32; o > 0; o >>= 1) { s1 += __shfl_down(s1, o); s2 += __shfl_down(s2, o); }
    if ((tid & 63) == 0) { r1[tid >> 6] = s1; r2[tid >> 6] = s2; }
    __syncthreads();
    s1 = r1[0] + r1[1] + r1[2] + r1[3];
    s2 = r2[0] + r2[1] + r2[2] + r2[3];
    const float mu = s1 * (1.f / HID);
    float var = s2 * (1.f / HID) - mu * mu;
    const float rs = rsqrtf(var + 1e-5f);
    xn[(long)bid * HID + tid]       = f2b((v0 - mu) * rs * nw[tid]       + nb[tid]);
    xn[(long)bid * HID + tid + 256] = f2b((v1 - mu) * rs * nw[tid + 256] + nb[tid + 256]);
    xn[(long)bid * HID + tid + 512] = f2b((v2 - mu) * rs * nw[tid + 512] + nb[tid + 512]);
    return;
  }

  // ---- transpose + cvt: fp32 W[K][N] -> bf16 Wt[Npad][K], zero pad ----
  bid -= MTOK;
  const float* W; u16* Wt; int K, N, nbx;
  if (bid < 2304)       {              W = W0; Wt = T0; K = 768;  N = 3072; nbx = 96; }
  else if (bid < 4800)  { bid -= 2304; W = W1; Wt = T1; K = 1536; N = 1568; nbx = 52; }
  else if (bid < 7104)  { bid -= 4800; W = W2; Wt = T2; K = 1536; N = 1536; nbx = 48; }
  else                  { bid -= 7104; W = W3; Wt = T3; K = 1536; N = 768;  nbx = 24; }
  const int tx = tid & 31, ty = tid >> 5;
  const int n0 = (bid % nbx) * 32, k0 = (bid / nbx) * 32;
#pragma unroll
  for (int r = 0; r < 4; ++r) {
    int kk = k0 + ty + r * 8;
    int nn = n0 + tx;
    tb[ty + r * 8][tx] = (nn < N) ? W[(long)kk * N + nn] : 0.f;
  }
  __syncthreads();
#pragma unroll
  for (int r = 0; r < 4; ++r) {
    int nn = n0 + ty + r * 8;
    int kk = k0 + tx;
    Wt[(long)nn * K + kk] = f2b(tb[tx][ty + r * 8]);
  }
}

// ---------------- GEMM: A[M][K] bf16 row-major, Bt[N][K] bf16, BMxBN tile ------
// 512 threads = 8 waves in 4x2; wave tile (BM/4)x(BN/2); BK=64 (2 k-slices).
// Double-buffered LDS, counted vmcnt, raw s_barrier, 3-bit XOR-swizzled LDS
// chunks (both-sides: pre-swizzled global source, linear DMA dest, swizzled
// ds_read), bijective chunked XCD remap (m204).
// 8 waves -> 24 resident waves/CU at 3 blocks/CU (vs 8-12 at 256 thr): TLP probe.
// EPI 0: cc<1536 -> Cb2[row*1536+cc]=bf16(v) (u half); else Cb[...]=bf16(v) (gate)
// EPI 1: cc<16 -> Bm, cc<32 -> Cm, cc<Nstore -> delta=softplus
// EPI 2: Cb = bf16(v * silu(gate)), gate = b2f(Eb[row*1536+cc])
// EPI 3: C0[row*768+cc] = v + E0[row*768+cc]
template <int BM, int BN, int EPI>
__global__ __launch_bounds__(512)
void gemm_bt(const u16* __restrict__ A, const u16* __restrict__ Bt,
             float* __restrict__ C0, float* __restrict__ C1, float* __restrict__ C2,
             u16* __restrict__ Cb, u16* __restrict__ Cb2,
             const float* __restrict__ E0, const u16* __restrict__ Eb,
             int K, int Nstore) {
  constexpr int BK = 64;
  constexpr int NT = 512;
  constexpr int WTM = BM / 4;        // wave tile M (4 wave-rows)
  constexpr int WTN = BN / 2;        // wave tile N (2 wave-cols)
  constexpr int FI = WTM / 16;       // A frags per wave
  constexpr int FJ = WTN / 16;       // B frags per wave
  constexpr int RPI = NT * 8 / BK;   // rows covered per stage instruction (=64)
  constexpr int NLD = BM / RPI + BN / RPI;  // DMA instrs per thread per K-step
  constexpr int KS = BK / 32;        // k-slices per K-step
  __shared__ u16 As[2][BM * BK];
  __shared__ u16 Bs[2][BN * BK];
  const int tid = threadIdx.x;
  const int lane = tid & 63;
  const int wave = tid >> 6;         // 0..7
  const int wm = wave >> 1, wn = wave & 1;
  const int l16 = lane & 15, l4 = lane >> 4;
  const int rsw = l16 & 7;           // 3-bit row swizzle for reads (row&7 == l16&7)

  // bijective chunked XCD remap (m204)
  const int nwg = (int)(gridDim.x * gridDim.y);
  const int orig = (int)(blockIdx.y * gridDim.x + blockIdx.x);
  const int q = nwg >> 3, r = nwg & 7, xc = orig & 7;
  const int logical = (xc < r ? xc * (q + 1) : r * (q + 1) + (xc - r) * q) + (orig >> 3);
  const long bm = (long)(logical / (int)gridDim.x) * BM;
  const long bn = (long)(logical % (int)gridDim.x) * BN;

  f32x4 acc[FI][FJ] = {};

  // staging: 512 thr x 16B = 64 rows of BK=64 per instr; stored chunk = tid&7
  // (linear LDS dest); fetch global chunk (tid&7)^(row&7) -> LDS[r][c] holds
  // data chunk c^(r&7).
  const int sr = tid >> 3;           // 0..63: row within 64-row group
  const int kg8 = (((tid & 7) ^ (sr & 7)) * 8);

  auto stage = [&](int buf, int k0) {
#pragma unroll
    for (int qq = 0; qq < BM / RPI; ++qq)
      gl2lds16(A + (bm + qq * RPI + sr) * K + k0 + kg8, &As[buf][(qq * NT + tid) * 8]);
#pragma unroll
    for (int qq = 0; qq < BN / RPI; ++qq)
      gl2lds16(Bt + (bn + qq * RPI + sr) * K + k0 + kg8, &Bs[buf][(qq * NT + tid) * 8]);
  };

  const int NK = K / BK;
  stage(0, 0);
  int cur = 0;
  for (int t = 0; t < NK; ++t) {
    if (t + 1 < NK) {
      stage(cur ^ 1, (t + 1) * BK);  // next tile's loads stay in flight
      vmwait<NLD>();                 // only wait for CURRENT tile's loads
    } else {
      vmwait<0>();
    }
    __builtin_amdgcn_s_barrier();    // cur buffer ready on all waves
    bf16x8 af[FI][KS], bfr[FJ][KS];
#pragma unroll
    for (int i = 0; i < FI; ++i)
#pragma unroll
      for (int ks = 0; ks < KS; ++ks)
        af[i][ks] = *(const bf16x8*)&As[cur][(wm * WTM + i * 16 + l16) * BK +
                                            (((ks * 4 + l4) ^ rsw) * 8)];
#pragma unroll
    for (int j = 0; j < FJ; ++j)
#pragma unroll
      for (int ks = 0; ks < KS; ++ks)
        bfr[j][ks] = *(const bf16x8*)&Bs[cur][(wn * WTN + j * 16 + l16) * BK +
                                             (((ks * 4 + l4) ^ rsw) * 8)];
#pragma unroll
    for (int ks = 0; ks < KS; ++ks)
#pragma unroll
      for (int i = 0; i < FI; ++i)
#pragma unroll
        for (int j = 0; j < FJ; ++j)
          acc[i][j] = __builtin_amdgcn_mfma_f32_16x16x32_bf16(af[i][ks], bfr[j][ks], acc[i][j], 0, 0, 0);
    __builtin_amdgcn_s_barrier();    // all reads of cur done before overwrite
    cur ^= 1;
  }

#pragma unroll
  for (int i = 0; i < FI; ++i) {
    const long rr = bm + wm * WTM + i * 16 + l4 * 4;
#pragma unroll
    for (int j = 0; j < FJ; ++j) {
      const int cc = (int)bn + wn * WTN + j * 16 + l16;
#pragma unroll
      for (int r = 0; r < 4; ++r) {
        const long row = rr + r;
        const float v = acc[i][j][r];
        if (EPI == 0) {
          if (cc < INNER) Cb2[row * INNER + cc] = f2b(v);
          else            Cb[row * INNER + (cc - INNER)] = f2b(v);
        } else if (EPI == 1) {
          if (cc < 16) C0[row * 16 + cc] = v;
          else if (cc < 32) C1[row * 16 + (cc - 16)] = v;
          else if (cc < Nstore) {
            float sp = (v > 20.f) ? v : log1pf(__expf(v));
            C2[row * 1536 + (cc - 32)] = sp;
          }
        } else if (EPI == 2) {
          float g = b2f(Eb[row * INNER + cc]);
          float s = g / (1.f + __expf(-g));
          Cb[row * INNER + cc] = f2b(v * s);
        } else {
          C0[row * 768 + cc] = v + E0[row * 768 + cc];
        }
      }
    }
  }
}

// ---------------- depthwise causal conv(K=4) + SiLU (bf16 in, bf16 out) --------
__global__ __launch_bounds__(256)
void conv_silu(const u16* __restrict__ ubr, const float* __restrict__ cw,
               u16* __restrict__ uf) {
  const int c = blockIdx.x * 256 + threadIdx.x;
  const long m = blockIdx.y;
  const int t = (int)(m & (SEQ - 1));
  const f32x4 wv = *(const f32x4*)&cw[c * 4];
  float acc = wv[3] * b2f(ubr[m * 1536 + c]);
  if (t >= 1) acc += wv[2] * b2f(ubr[(m - 1) * 1536 + c]);
  if (t >= 2) acc += wv[1] * b2f(ubr[(m - 2) * 1536 + c]);
  if (t >= 3) acc += wv[0] * b2f(ubr[(m - 3) * 1536 + c]);
  const float s = acc / (1.f + __expf(-acc));
  uf[m * 1536 + c] = f2b(s);
}

// ---------------- scan phase A: per-chunk (P, Q) from h=0, 4 states/thread ------
__global__ __launch_bounds__(256)
void scan_phaseA(const float* __restrict__ dlt, const u16* __restrict__ uf,
                 const float* __restrict__ Bm, const float* __restrict__ A_log,
                 float* __restrict__ P, float* __restrict__ Q) {
  const int tid = threadIdx.x;
  const int cl = tid >> 2;
  const int sg = tid & 3;
  const int c = blockIdx.x * 64 + cl;
  const int b = blockIdx.y;
  const int ch = blockIdx.z;
  float a2[4];
#pragma unroll
  for (int j = 0; j < 4; ++j) a2[j] = -__expf(A_log[sg * 4 + j]) * LOG2E;
  float h[4] = {0.f, 0.f, 0.f, 0.f};
  float sumd = 0.f;
  const long base = (long)b * SEQ + (long)ch * CHUNK;
  for (int t = 0; t < CHUNK; ++t) {
    const long m = base + t;
    const float d = dlt[m * 1536 + c];
    const float du = d * b2f(uf[m * 1536 + c]);
    sumd += d;
    const f32x4 Bv = *(const f32x4*)&Bm[m * 16 + sg * 4];
#pragma unroll
    for (int j = 0; j < 4; ++j) {
      const float e = exp2f(a2[j] * d);
      h[j] = e * h[j] + du * Bv[j];
    }
  }
  const long sb = (((long)b * NCHUNK + ch) * NST + sg * 4) * 1536 + c;
#pragma unroll
  for (int j = 0; j < 4; ++j) {
    Q[sb + (long)j * 1536] = h[j];
    P[sb + (long)j * 1536] = exp2f(a2[j] * sumd);
  }
}

// ---------------- scan phase B: serial combine over chunks (hs aliases P) -------
__global__ __launch_bounds__(256)
void scan_phaseB(float* __restrict__ P, const float* __restrict__ Q) {
  const long g = (long)blockIdx.x * 256 + threadIdx.x;   // BATCH*NST*INNER
  const int c = (int)(g % 1536);
  const int n = (int)((g / 1536) % NST);
  const int b = (int)(g / (1536 * NST));
  float h = 0.f;
  for (int ch = 0; ch < NCHUNK; ++ch) {
    const long idx = (((long)b * NCHUNK + ch) * NST + n) * 1536 + c;
    const float p = P[idx];
    const float q = Q[idx];
    P[idx] = h;              // hs written in place of P (read-before-write)
    h = p * h + q;
  }
}

// ---------------- scan phase C: replay with true h_start, emit ys bf16 ----------
__global__ __launch_bounds__(256)
void scan_phaseC(const float* __restrict__ dlt, const u16* __restrict__ uf,
                 const float* __restrict__ Bm, const float* __restrict__ Cm,
                 const float* __restrict__ A_log, const float* __restrict__ Dv,
                 const float* __restrict__ hs, u16* __restrict__ ys) {
  const int tid = threadIdx.x;
  const int cl = tid >> 2;
  const int sg = tid & 3;
  const int c = blockIdx.x * 64 + cl;
  const int b = blockIdx.y;
  const int ch = blockIdx.z;
  float a2[4];
#pragma unroll
  for (int j = 0; j < 4; ++j) a2[j] = -__expf(A_log[sg * 4 + j]) * LOG2E;
  float h[4];
  const long sb = (((long)b * NCHUNK + ch) * NST + sg * 4) * 1536 + c;
#pragma unroll
  for (int j = 0; j < 4; ++j) h[j] = hs[sb + (long)j * 1536];
  const float Dc = Dv[c];
  const long base = (long)b * SEQ + (long)ch * CHUNK;
  for (int t = 0; t < CHUNK; ++t) {
    const long m = base + t;
    const float d = dlt[m * 1536 + c];
    const float uu = b2f(uf[m * 1536 + c]);
    const float du = d * uu;
    const f32x4 Bv = *(const f32x4*)&Bm[m * 16 + sg * 4];
    const f32x4 Cv = *(const f32x4*)&Cm[m * 16 + sg * 4];
    float y = (sg == 0) ? Dc * uu : 0.f;
#pragma unroll
    for (int j = 0; j < 4; ++j) {
      const float e = exp2f(a2[j] * d);
      h[j] = e * h[j] + du * Bv[j];
      y += h[j] * Cv[j];
    }
    y += __shfl_xor(y, 1);
    y += __shfl_xor(y, 2);
    if (sg == 0) ys[m * 1536 + c] = f2b(y);
  }
}

extern "C" void kernel_launch(void* const* d_in, const int* in_sizes, int n_in,
                              void* d_out, int out_size, void* d_ws, size_t ws_size,
                              hipStream_t stream) {
  const float* x     = (const float*)d_in[0];
  const float* nw    = (const float*)d_in[1];
  const float* nb    = (const float*)d_in[2];
  const float* W_in  = (const float*)d_in[3];
  const float* cw    = (const float*)d_in[4];
  const float* W_xp  = (const float*)d_in[5];
  const float* A_log = (const float*)d_in[6];
  const float* Dv    = (const float*)d_in[7];
  const float* W_so  = (const float*)d_in[8];
  const float* W_out = (const float*)d_in[9];
  float* out = (float*)d_out;

  char* w = (char*)d_ws;
  auto alloc = [&](size_t bytes) {
    char* p = w;
    w += (bytes + 255) & ~(size_t)255;
    return p;
  };
  u16*   xn    = (u16*)  alloc((size_t)MTOK * HID * 2);
  u16*   WtIn  = (u16*)  alloc((size_t)3072 * 768 * 2);
  u16*   ubr   = (u16*)  alloc((size_t)MTOK * 1536 * 2);   // u half pre-conv, bf16
  u16*   gb    = (u16*)  alloc((size_t)MTOK * 1536 * 2);   // gate half, bf16
  u16*   uf    = (u16*)  alloc((size_t)MTOK * 1536 * 2);   // conv+silu output, bf16
  u16*   WtXp  = (u16*)  alloc((size_t)1664 * 1536 * 2);
  float* Bmv   = (float*)alloc((size_t)MTOK * 16 * 4);
  float* Cmv   = (float*)alloc((size_t)MTOK * 16 * 4);
  float* dlt   = (float*)alloc((size_t)MTOK * 1536 * 4);
  float* P     = (float*)alloc((size_t)BATCH * NCHUNK * NST * 1536 * 4);  // becomes hs
  float* Q     = (float*)alloc((size_t)BATCH * NCHUNK * NST * 1536 * 4);
  u16*   ys    = (u16*)  alloc((size_t)MTOK * 1536 * 2);
  u16*   WtSo  = (u16*)  alloc((size_t)1536 * 1536 * 2);
  u16*   zb    = (u16*)  alloc((size_t)MTOK * 1536 * 2);
  u16*   WtOut = (u16*)  alloc((size_t)768 * 1536 * 2);

  // merged LN + 4 weight transposes
  prologue<<<12352, 256, 0, stream>>>(x, nw, nb, xn,
                                      W_in, WtIn, W_xp, WtXp,
                                      W_so, WtSo, W_out, WtOut);

  // gemm0: 4096x3072, K=768  -> 128x64 tile, 48x32 = 1536 blocks, 512 thr
  gemm_bt<128, 64, 0><<<dim3(48, 32), 512, 0, stream>>>(xn, WtIn, nullptr, nullptr, nullptr, gb, ubr, nullptr, nullptr, 768, 3072);
  conv_silu<<<dim3(6, MTOK), 256, 0, stream>>>(ubr, cw, uf);
  // gemm1: 4096x1664, K=1536 -> 128x64 tile, 26x32 = 832 blocks, 512 thr
  gemm_bt<128, 64, 1><<<dim3(26, 32), 512, 0, stream>>>(uf, WtXp, Bmv, Cmv, dlt, nullptr, nullptr, nullptr, nullptr, 1536, 1568);
  scan_phaseA<<<dim3(24, 2, NCHUNK), 256, 0, stream>>>(dlt, uf, Bmv, A_log, P, Q);
  scan_phaseB<<<192, 256, 0, stream>>>(P, Q);
  scan_phaseC<<<dim3(24, 2, NCHUNK), 256, 0, stream>>>(dlt, uf, Bmv, Cmv, A_log, Dv, P, ys);
  // gemm2: 4096x1536, K=1536 -> 128x64 tile, 24x32 = 768 blocks, 512 thr
  gemm_bt<128, 64, 2><<<dim3(24, 32), 512, 0, stream>>>(ys, WtSo, nullptr, nullptr, nullptr, zb, nullptr, nullptr, gb, 1536, 1536);
  // gemm3: 4096x768,  K=1536 -> 64x64 tile, 12x64 = 768 blocks, 512 thr
  gemm_bt<64, 64, 3><<<dim3(12, 64), 512, 0, stream>>>(zb, WtOut, out, nullptr, nullptr, nullptr, nullptr, x, nullptr, 1536, 768);
}